// Round 8
// baseline (136.912 us; speedup 1.0000x reference)
//
#include <hip/hip_runtime.h>
#include <math.h>

#define NSV 512

// ---------------------------------------------------------------------------
// Persistent-kernel infrastructure (proven correct+fast pattern from R6/R7):
// cross-block ws data uses RELAXED+AGENT atomics (per-access coherent, no
// cache-wide invalidates); barrier = vmcnt drain + relaxed atomic counter.
// Weights/biases are read-only inputs -> plain cached loads.
// ---------------------------------------------------------------------------
__device__ unsigned g_bar  = 0;
__device__ unsigned g_exit = 0;

__device__ __forceinline__ float gload(const float* p) {
    return __hip_atomic_load(p, __ATOMIC_RELAXED, __HIP_MEMORY_SCOPE_AGENT);
}
__device__ __forceinline__ void gstore(float* p, float v) {
    __hip_atomic_store(p, v, __ATOMIC_RELAXED, __HIP_MEMORY_SCOPE_AGENT);
}

__device__ __forceinline__ void gsync(unsigned target) {
    asm volatile("s_waitcnt vmcnt(0)" ::: "memory");
    __syncthreads();
    if (threadIdx.x == 0) {
        atomicAdd(&g_bar, 1u);
        while (__hip_atomic_load(&g_bar, __ATOMIC_RELAXED,
                                 __HIP_MEMORY_SCOPE_AGENT) < target)
            __builtin_amdgcn_s_sleep(4);
    }
    __syncthreads();
}

// ---------------------------------------------------------------------------
// P0 role: pair-stream chain, one block per column j, entirely in LDS.
// Emits pme0..pme3 (spin means), sv0 row j, expv[j]. p never hits memory.
// ---------------------------------------------------------------------------
__device__ void pchain_role(int j, const float* __restrict__ r,
                            const float* __restrict__ apos,
                            const float* __restrict__ W0w, const float* __restrict__ W0b,
                            const float* __restrict__ W1w, const float* __restrict__ W1b,
                            const float* __restrict__ W2w, const float* __restrict__ W2b,
                            float* __restrict__ sv0, float* __restrict__ expv,
                            float* __restrict__ pme0, float* __restrict__ pme1,
                            float* __restrict__ pme2, float* __restrict__ pme3,
                            float* sh)
{
    float* rL   = sh;            // 384
    float* W0l  = sh + 384;      // 256
    float* shex = sh + 640;      // 32
    float* p0c  = sh + 672;      // 512
    float* PA   = sh + 1184;     // 128*68 = 8704
    float* Wbuf = sh + 9888;     // 4096
    const int t = threadIdx.x;
    const int i  = t >> 2;
    const int o0 = (t & 3) * 16;

    if (t < 384) rL[t] = r[t];
    for (int idx = t; idx < 4096; idx += 512) Wbuf[idx] = W1w[idx];
    if (t < 256) W0l[t] = W0w[t];
    __syncthreads();

    const float rjx = rL[j*3+0], rjy = rL[j*3+1], rjz = rL[j*3+2];
    if (t < 128) {
        const int ii = t;
        float dx = rjx - rL[ii*3+0], dy = rjy - rL[ii*3+1], dz = rjz - rL[ii*3+2];
        float len = (ii == j) ? 0.f : sqrtf(dx*dx + dy*dy + dz*dz);
        p0c[ii*4+0]=dx; p0c[ii*4+1]=dy; p0c[ii*4+2]=dz; p0c[ii*4+3]=len;
    } else if (t < 160) {
        const int k = t - 128;
        float dx = rjx - apos[k*3+0], dy = rjy - apos[k*3+1], dz = rjz - apos[k*3+2];
        float len = sqrtf(dx*dx + dy*dy + dz*dz);
        gstore(&sv0[(size_t)j*128 + k*4 + 0], dx);
        gstore(&sv0[(size_t)j*128 + k*4 + 1], dy);
        gstore(&sv0[(size_t)j*128 + k*4 + 2], dz);
        gstore(&sv0[(size_t)j*128 + k*4 + 3], len);
        shex[k] = expf(-len);
    }
    __syncthreads();

    {   // layer0: PA[i][o] = tanh(p0c[i] @ W0 + b0)
        const float x0=p0c[i*4+0], x1=p0c[i*4+1], x2=p0c[i*4+2], x3=p0c[i*4+3];
        #pragma unroll
        for (int k = 0; k < 16; ++k) {
            const int o = o0 + k;
            float acc = W0b[o];
            acc = fmaf(x0, W0l[o],     acc);
            acc = fmaf(x1, W0l[64+o],  acc);
            acc = fmaf(x2, W0l[128+o], acc);
            acc = fmaf(x3, W0l[192+o], acc);
            PA[i*68+o] = tanhf(acc);
        }
    }
    if (t < 8) {
        const int spin = t >> 2, c = t & 3;
        float s = 0.f;
        #pragma unroll 8
        for (int k = 0; k < 64; ++k) s += p0c[(spin*64+k)*4 + c];
        gstore(&pme0[j*8 + t], s * 0.015625f);
    }
    if (t == 8) {
        float s = 0.f;
        #pragma unroll 8
        for (int k = 0; k < 32; ++k) s += shex[k];
        gstore(&expv[j], s);
    }
    __syncthreads();

    // pme1 + layer1
    if (t < 128) {
        const int spin = t >> 6, c = t & 63;
        float s = 0.f;
        #pragma unroll 8
        for (int k = 0; k < 64; ++k) s += PA[(spin*64+k)*68 + c];
        gstore(&pme1[j*128 + t], s * 0.015625f);
    }
    float acc[16], res[16];
    const float* pa = PA + i*68;
    {
        #pragma unroll
        for (int k = 0; k < 16; ++k) acc[k] = W1b[o0+k];
        #pragma unroll 4
        for (int c = 0; c < 64; ++c) {
            const float av = pa[c];
            const float* wr = Wbuf + c*64 + o0;
            float4 wa = *reinterpret_cast<const float4*>(wr);
            float4 wb = *reinterpret_cast<const float4*>(wr+4);
            float4 wc = *reinterpret_cast<const float4*>(wr+8);
            float4 wd = *reinterpret_cast<const float4*>(wr+12);
            acc[0] =fmaf(av,wa.x,acc[0]);  acc[1] =fmaf(av,wa.y,acc[1]);
            acc[2] =fmaf(av,wa.z,acc[2]);  acc[3] =fmaf(av,wa.w,acc[3]);
            acc[4] =fmaf(av,wb.x,acc[4]);  acc[5] =fmaf(av,wb.y,acc[5]);
            acc[6] =fmaf(av,wb.z,acc[6]);  acc[7] =fmaf(av,wb.w,acc[7]);
            acc[8] =fmaf(av,wc.x,acc[8]);  acc[9] =fmaf(av,wc.y,acc[9]);
            acc[10]=fmaf(av,wc.z,acc[10]); acc[11]=fmaf(av,wc.w,acc[11]);
            acc[12]=fmaf(av,wd.x,acc[12]); acc[13]=fmaf(av,wd.y,acc[13]);
            acc[14]=fmaf(av,wd.z,acc[14]); acc[15]=fmaf(av,wd.w,acc[15]);
        }
        #pragma unroll
        for (int k = 0; k < 16; ++k) res[k] = pa[o0+k];
    }
    __syncthreads();
    #pragma unroll
    for (int k = 0; k < 16; ++k) PA[i*68+o0+k] = tanhf(acc[k]) + res[k];
    __syncthreads();

    // pme2 + restage W2
    if (t < 128) {
        const int spin = t >> 6, c = t & 63;
        float s = 0.f;
        #pragma unroll 8
        for (int k = 0; k < 64; ++k) s += PA[(spin*64+k)*68 + c];
        gstore(&pme2[j*128 + t], s * 0.015625f);
    }
    for (int idx = t; idx < 4096; idx += 512) Wbuf[idx] = W2w[idx];
    __syncthreads();

    {   // layer2
        #pragma unroll
        for (int k = 0; k < 16; ++k) acc[k] = W2b[o0+k];
        #pragma unroll 4
        for (int c = 0; c < 64; ++c) {
            const float av = pa[c];
            const float* wr = Wbuf + c*64 + o0;
            float4 wa = *reinterpret_cast<const float4*>(wr);
            float4 wb = *reinterpret_cast<const float4*>(wr+4);
            float4 wc = *reinterpret_cast<const float4*>(wr+8);
            float4 wd = *reinterpret_cast<const float4*>(wr+12);
            acc[0] =fmaf(av,wa.x,acc[0]);  acc[1] =fmaf(av,wa.y,acc[1]);
            acc[2] =fmaf(av,wa.z,acc[2]);  acc[3] =fmaf(av,wa.w,acc[3]);
            acc[4] =fmaf(av,wb.x,acc[4]);  acc[5] =fmaf(av,wb.y,acc[5]);
            acc[6] =fmaf(av,wb.z,acc[6]);  acc[7] =fmaf(av,wb.w,acc[7]);
            acc[8] =fmaf(av,wc.x,acc[8]);  acc[9] =fmaf(av,wc.y,acc[9]);
            acc[10]=fmaf(av,wc.z,acc[10]); acc[11]=fmaf(av,wc.w,acc[11]);
            acc[12]=fmaf(av,wd.x,acc[12]); acc[13]=fmaf(av,wd.y,acc[13]);
            acc[14]=fmaf(av,wd.z,acc[14]); acc[15]=fmaf(av,wd.w,acc[15]);
        }
        #pragma unroll
        for (int k = 0; k < 16; ++k) res[k] = pa[o0+k];
    }
    __syncthreads();
    #pragma unroll
    for (int k = 0; k < 16; ++k) PA[i*68+o0+k] = tanhf(acc[k]) + res[k];
    __syncthreads();

    if (t < 128) {
        const int spin = t >> 6, c = t & 63;
        float s = 0.f;
        #pragma unroll 8
        for (int k = 0; k < 64; ++k) s += PA[(spin*64+k)*68 + c];
        gstore(&pme3[j*128 + t], s * 0.015625f);
    }
}

// ---------------------------------------------------------------------------
// P1..P4 role: s-stream GEMM (R7's a2 body). 256 blocks, tile 4e x 64o,
// K split in halves across wave groups. smean from sv0 cols (L0) or psum.
// ---------------------------------------------------------------------------
template<int FS, int FP, bool L0>
__device__ void a2_role(int b, const float* __restrict__ svIn,
                        const float* __restrict__ pmeIn,
                        const float* __restrict__ psumIn,
                        const float* __restrict__ Vw, const float* __restrict__ Vb,
                        float* __restrict__ svOut, float* __restrict__ psumOut,
                        float* sh)
{
    constexpr int KP  = 2*FP + FS;        // 136 (L0) or 640
    constexpr int KP2 = KP/2;
    float* As  = sh;                      // 4*KP
    float* smL = sh + 4*KP;               // 2*FS
    float* red = smL + 2*FS;              // 512
    float* t1L = red + 512;               // 64
    const int t  = threadIdx.x;
    const int et = b >> 3;
    const int e0 = et * 4;
    const int o0 = (b & 7) * 64;
    const int ol = t & 63;
    const int o  = o0 + ol;
    const int wv = t >> 6;

    for (int idx = t; idx < 4*2*FP; idx += 512)
        As[(idx/(2*FP))*KP + idx%(2*FP)] =
            gload(&pmeIn[(size_t)(e0 + idx/(2*FP))*(2*FP) + idx%(2*FP)]);
    for (int idx = t; idx < 4*FS; idx += 512)
        As[(idx/FS)*KP + 2*FP + idx%FS] =
            gload(&svIn[(size_t)(e0 + idx/FS)*FS + idx%FS]);
    if (L0) {
        for (int idx = t; idx < 2*FS; idx += 512) {
            const int col = (idx < FS) ? idx : idx - FS;
            const int i0  = (idx < FS) ? 0 : 64;
            float s = 0.f;
            #pragma unroll 8
            for (int k = 0; k < 64; ++k)
                s += gload(&svIn[(size_t)(i0+k)*FS + col]);
            smL[idx] = s * 0.015625f;
        }
    } else {
        for (int idx = t; idx < 2*FS; idx += 512) {
            const int col = (idx < FS) ? idx : idx - FS;
            const int r0  = (idx < FS) ? 0 : 16;
            float s = 0.f;
            #pragma unroll
            for (int k = 0; k < 16; ++k)
                s += gload(&psumIn[(size_t)(r0+k)*NSV + col]);
            smL[idx] = s * 0.015625f;
        }
    }
    __syncthreads();

    {   // t1 partials over 8 waves
        constexpr int TI = (2*FS)/8;
        float a1 = 0.f;
        const float* Wp = Vw + (size_t)(wv*TI)*NSV + o;
        const float* mp = smL + wv*TI;
        #pragma unroll 8
        for (int k = 0; k < TI; ++k) a1 = fmaf(mp[k], Wp[(size_t)k*NSV], a1);
        red[wv*64 + ol] = a1;
    }
    __syncthreads();
    if (t < 64) {
        float s = Vb[o0 + t];
        #pragma unroll
        for (int g = 0; g < 8; ++g) s += red[g*64 + t];
        t1L[t] = s;
    }
    __syncthreads();

    const int e_l = wv & 3, kh = wv >> 2;
    {   // main GEMM, K halves across wave groups
        float a2 = (kh == 0) ? t1L[ol] : 0.f;
        const float* Ap = As + e_l*KP + kh*KP2;          // wave-uniform base
        const float* Wp = Vw + (size_t)(2*FS + kh*KP2)*NSV + o;
        #pragma unroll 16
        for (int k = 0; k < KP2; ++k)
            a2 = fmaf(Ap[k], Wp[(size_t)k*NSV], a2);
        red[wv*64 + ol] = a2;
    }
    __syncthreads();
    float v = 0.f;
    if (t < 256) {
        v = tanhf(red[(t>>6)*64 + (t&63)] + red[((t>>6)+4)*64 + (t&63)]);
        gstore(&svOut[(size_t)(e0 + (t>>6))*NSV + o0 + (t&63)], v);
    }
    if (psumOut) {
        __syncthreads();
        if (t < 256) red[t] = v;
        __syncthreads();
        if (t < 64) {
            float s = red[t] + red[64+t] + red[128+t] + red[192+t];
            gstore(&psumOut[(size_t)et*NSV + o0 + t], s);
        }
    }
}

// ---------------------------------------------------------------------------
// P5 role: heads + orbital matrices, per electron.
// ---------------------------------------------------------------------------
__device__ void headsw_role(int e, const float* __restrict__ svF,
                            const float* __restrict__ vhu_w, const float* __restrict__ vhu_b,
                            const float* __restrict__ vhd_w, const float* __restrict__ vhd_b,
                            const float* __restrict__ wu_w,  const float* __restrict__ wu_b,
                            const float* __restrict__ wd_w,  const float* __restrict__ wd_b,
                            const float* __restrict__ expv,  float* __restrict__ orb,
                            float* sh)
{
    float* row  = sh;          // 512
    float* redH = sh + 512;    // 512
    float* tmpL = sh + 1024;   // 256
    const int spin = e >> 6;
    const int t = threadIdx.x;
    row[t] = gload(&svF[(size_t)e*NSV + t]);
    __syncthreads();

    const float* W1 = spin ? vhd_w : vhu_w;
    const float* B1 = spin ? vhd_b : vhu_b;
    {
        const int o = t & 255, kc = t >> 8;
        float acc = kc ? 0.f : B1[o];
        const float* Wp = W1 + (size_t)(kc*256)*256 + o;
        const float* rp = row + kc*256;
        #pragma unroll 8
        for (int f = 0; f < 256; ++f)
            acc = fmaf(rp[f], Wp[(size_t)f*256], acc);
        redH[t] = acc;
    }
    __syncthreads();
    if (t < 256) tmpL[t] = redH[t] + redH[256 + t];
    __syncthreads();

    const float* W2 = spin ? wd_w : wu_w;
    const float* B2 = spin ? wd_b : wu_b;
    {
        const int o = t & 63, kc = t >> 6;
        float acc = 0.f;
        const float* Wp = W2 + (size_t)(kc*32)*64 + o;
        const float* tp = tmpL + kc*32;
        #pragma unroll
        for (int f = 0; f < 32; ++f)
            acc = fmaf(tp[f], Wp[(size_t)f*64], acc);
        redH[kc*64 + o] = acc;
    }
    __syncthreads();
    if (t < 64) {
        float s = B2[t];
        #pragma unroll
        for (int g = 0; g < 8; ++g) s += redH[g*64 + t];
        gstore(&orb[(size_t)e*64 + t], s * gload(&expv[e]));
    }
}

// ---------------------------------------------------------------------------
// P6 role: two 64x64 log|det| LU with partial pivoting (block 0).
// DPP packed argmax, bit-cast readlane broadcasts, deferred log.
// ---------------------------------------------------------------------------
__device__ __forceinline__ int imax2(int a, int b) { return a > b ? a : b; }
__device__ __forceinline__ float readlane_f(float x, int lane) {
    return __int_as_float(__builtin_amdgcn_readlane(__float_as_int(x), lane));
}

__device__ void det_role(const float* __restrict__ orb, float* __restrict__ out,
                         float* sh)
{
    const int t = threadIdx.x;
    if (t < 128) {
        const int w = t >> 6;
        const int lane = t & 63;
        const float* M = orb + (size_t)w*4096 + (size_t)lane*64;
        float rr[64];
        #pragma unroll
        for (int j = 0; j < 64; ++j) rr[j] = gload(M + j);
        float pv_mine = 1.f;
        bool active = true;
        #pragma unroll
        for (int k = 0; k < 64; ++k) {
            int bits = (int)(__float_as_uint(rr[k]) & 0x7FFFFFC0u);
            int v = active ? (bits | lane) : lane;
            int tmp;
            tmp = __builtin_amdgcn_update_dpp(0, v, 0xB1,  0xF, 0xF, true); v = imax2(v, tmp);
            tmp = __builtin_amdgcn_update_dpp(0, v, 0x4E,  0xF, 0xF, true); v = imax2(v, tmp);
            tmp = __builtin_amdgcn_update_dpp(0, v, 0x141, 0xF, 0xF, true); v = imax2(v, tmp);
            tmp = __builtin_amdgcn_update_dpp(0, v, 0x140, 0xF, 0xF, true); v = imax2(v, tmp);
            tmp = __builtin_amdgcn_update_dpp(0, v, 0x142, 0xF, 0xF, true); v = imax2(v, tmp);
            tmp = __builtin_amdgcn_update_dpp(0, v, 0x143, 0xF, 0xF, true); v = imax2(v, tmp);
            const int idx = __builtin_amdgcn_readlane(v, 63) & 63;
            const float piv = readlane_f(rr[k], idx);
            pv_mine = (lane == k) ? piv : pv_mine;
            const float linv = __builtin_amdgcn_rcpf(piv);
            const float l = (active && lane != idx) ? rr[k]*linv : 0.f;
            if (lane == idx) active = false;
            #pragma unroll
            for (int j = k+1; j < 64; ++j)
                rr[j] = fmaf(-l, readlane_f(rr[j], idx), rr[j]);
        }
        float lg = logf(fabsf(pv_mine));
        #pragma unroll
        for (int off = 32; off; off >>= 1) lg += __shfl_down(lg, off);
        if (lane == 0) sh[w] = lg;
    }
    __syncthreads();
    if (t == 0) gstore(&out[0], sh[0] + sh[1]);
}

// ---------------------------------------------------------------------------
// The single persistent kernel: 256 blocks x 512 threads, 7 phases.
// ---------------------------------------------------------------------------
__global__ void __launch_bounds__(512)
fused_ansatz(const float* __restrict__ r,    const float* __restrict__ apos,
             const float* __restrict__ V0w,  const float* __restrict__ V0b,
             const float* __restrict__ W0w,  const float* __restrict__ W0b,
             const float* __restrict__ V1w,  const float* __restrict__ V1b,
             const float* __restrict__ W1w,  const float* __restrict__ W1b,
             const float* __restrict__ V2w,  const float* __restrict__ V2b,
             const float* __restrict__ W2w,  const float* __restrict__ W2b,
             const float* __restrict__ afw,  const float* __restrict__ afb,
             const float* __restrict__ vhuw, const float* __restrict__ vhub,
             const float* __restrict__ vhdw, const float* __restrict__ vhdb,
             const float* __restrict__ wuw,  const float* __restrict__ wub,
             const float* __restrict__ wdw,  const float* __restrict__ wdb,
             float* __restrict__ ws, float* __restrict__ out)
{
    __shared__ __align__(16) float sh[13984];
    const int b = blockIdx.x;
    const int t = threadIdx.x;

    float* sv0  = ws;              // 16384
    float* svA  = sv0  + 16384;    // 65536
    float* svB  = svA  + 65536;    // 65536
    float* expv = svB  + 65536;    // 128
    float* pme0 = expv + 128;      // 1024
    float* pme1 = pme0 + 1024;     // 16384
    float* pme2 = pme1 + 16384;    // 16384
    float* pme3 = pme2 + 16384;    // 16384
    float* psA  = pme3 + 16384;    // 16384
    float* psB  = psA  + 16384;    // 16384
    float* orb  = psB  + 16384;    // 8192

    // P0: pair chain + geometry (blocks 0..127)
    if (b < 128)
        pchain_role(b, r, apos, W0w, W0b, W1w, W1b, W2w, W2b,
                    sv0, expv, pme0, pme1, pme2, pme3, sh);
    gsync(256);

    // P1..P4: s-stream GEMMs (all 256 blocks)
    a2_role<128, 4, true  >(b, sv0, pme0, nullptr, V0w, V0b, svA, psA, sh);
    gsync(512);
    a2_role<512, 64, false>(b, svA, pme1, psA, V1w, V1b, svB, psB, sh);
    gsync(768);
    a2_role<512, 64, false>(b, svB, pme2, psB, V2w, V2b, svA, psA, sh);
    gsync(1024);
    a2_role<512, 64, false>(b, svA, pme3, psA, afw, afb, svB, nullptr, sh);
    gsync(1280);

    // P5: heads + orbitals (blocks 0..127)
    if (b < 128)
        headsw_role(b, svB, vhuw, vhub, vhdw, vhdb, wuw, wub, wdw, wdb,
                    expv, orb, sh);
    gsync(1536);

    // P6: determinants (block 0)
    if (b == 0) det_role(orb, out, sh);

    // exit protocol: reset barrier state for the next graph replay
    __syncthreads();
    if (t == 0) {
        atomicAdd(&g_exit, 1u);
        if (b == 0) {
            while (__hip_atomic_load(&g_exit, __ATOMIC_RELAXED,
                                     __HIP_MEMORY_SCOPE_AGENT) < 256u)
                __builtin_amdgcn_s_sleep(4);
            atomicExch(&g_bar,  0u);
            atomicExch(&g_exit, 0u);
        }
    }
}

// ---------------------------------------------------------------------------
extern "C" void kernel_launch(void* const* d_in, const int* in_sizes, int n_in,
                              void* d_out, int out_size, void* d_ws, size_t ws_size,
                              hipStream_t stream)
{
    const float* r    = (const float*)d_in[0];
    const float* apos = (const float*)d_in[1];
    const float* V0w  = (const float*)d_in[2];
    const float* V0b  = (const float*)d_in[3];
    const float* W0w  = (const float*)d_in[4];
    const float* W0b  = (const float*)d_in[5];
    const float* V1w  = (const float*)d_in[6];
    const float* V1b  = (const float*)d_in[7];
    const float* W1w  = (const float*)d_in[8];
    const float* W1b  = (const float*)d_in[9];
    const float* V2w  = (const float*)d_in[10];
    const float* V2b  = (const float*)d_in[11];
    const float* W2w  = (const float*)d_in[12];
    const float* W2b  = (const float*)d_in[13];
    const float* afw  = (const float*)d_in[14];
    const float* afb  = (const float*)d_in[15];
    const float* vhuw = (const float*)d_in[16];
    const float* vhub = (const float*)d_in[17];
    const float* vhdw = (const float*)d_in[18];
    const float* vhdb = (const float*)d_in[19];
    const float* wuw  = (const float*)d_in[20];
    const float* wub  = (const float*)d_in[21];
    const float* wdw  = (const float*)d_in[22];
    const float* wdb  = (const float*)d_in[23];

    fused_ansatz<<<dim3(256), dim3(512), 0, stream>>>(
        r, apos, V0w, V0b, W0w, W0b, V1w, V1b, W1w, W1b,
        V2w, V2b, W2w, W2b, afw, afb, vhuw, vhub, vhdw, vhdb,
        wuw, wub, wdw, wdb, (float*)d_ws, (float*)d_out);
}